// Round 11
// baseline (36.658 us; speedup 1.0000x reference)
//
#include <hip/hip_runtime.h>
#include <hip/hip_bf16.h>

typedef __attribute__((ext_vector_type(8))) short short8;
typedef __attribute__((ext_vector_type(4))) float f32x4;

#define NBATCH 32
#define NT 512
#define NS 512
#define ND 1024
#define BM 128               /* target rows per tile */
#define BN 256               /* support rows per tile */
#define BK 32                /* elems per phase (one MFMA k-depth) */
#define NK (ND / BK)         /* 32 phases */
#define ATSZ (BM * BK)       /* 4096 shorts per A tile buffer */
#define BTSZ (BN * BK)       /* 8192 shorts per B tile buffer */

__device__ __forceinline__ short f2bf(float f) {
    union { __hip_bfloat16 h; short s; } u;
    u.h = __float2bfloat16(f);
    return u.s;
}

__device__ __forceinline__ short8 cvt8(float4 a, float4 b) {
    short8 r;
    r[0] = f2bf(a.x); r[1] = f2bf(a.y); r[2] = f2bf(a.z); r[3] = f2bf(a.w);
    r[4] = f2bf(b.x); r[5] = f2bf(b.y); r[6] = f2bf(b.z); r[7] = f2bf(b.w);
    return r;
}

__device__ __forceinline__ float ssq4(float s, float4 a) {
    return fmaf(a.x, a.x, fmaf(a.y, a.y, fmaf(a.z, a.z, fmaf(a.w, a.w, s))));
}

// r10 geometry (35.2us, traffic-optimal: 128x256 tile, grid 256 = 1
// block/CU, reads 384MB) + r9's CROSS-BARRIER FRAGMENT PREFETCH. At r10's
// 1 block/CU the barrier convoy is NAKED (no second block overlaps the
// drain; measured phase ~2600cy vs ~1050cy of actual port+pipe work).
// r9's structure was null at 2 blocks/CU BECAUSE the second block masked
// the convoy - this is the A/B. Triple-buffered tiles: phase k MFMAs tile
// k purely from registers (frags read last phase -> zero LDS dependency at
// barrier exit), issues tile k+1's frag reads (needed only after next
// barrier -> full phase of slack), STORETs tile k+2 (vmcnt distance = 1
// phase >> HBM latency), LOADTs tile k+3. Unchanged, proven: 512 thr = 8
// waves (2x4), wave 64x64 via 4x4 frags of v_mfma_f32_16x16x32_bf16; bf16
// cvt once at staging; lgkmcnt(0)-only s_barrier fences (globals never
// drained in-loop); swizzle (u + (row>>1))&3 both sides (0 conflicts);
// fused row sum-of-squares (norms free); XCD-chunked grid (256 % 8 == 0).
__global__ __launch_bounds__(512, 2)
void paircos_mfma(const float* __restrict__ sup, const float* __restrict__ tgt,
                  float* __restrict__ out) {
    __shared__ __align__(16) short As[3 * ATSZ]; // targets tiles (3 x 8KB)
    __shared__ __align__(16) short Bs[3 * BTSZ]; // supports tiles (3 x 16KB)
    __shared__ float tn[BM];
    __shared__ float sn[BN];

    const int tid = threadIdx.x;
    // XCD-chunked bijective swizzle (256 blocks)
    const int l    = blockIdx.x;
    const int wgid = (l & 7) * 32 + (l >> 3);
    const int b    = wgid >> 3;        // batch
    const int til  = wgid & 7;         // 4 t-tiles x 2 s-tiles
    const int bt0  = (til >> 1) * BM;
    const int bs0  = (til & 1) * BN;

    // staging: thread owns 8-elem segment seg of A row srow and B rows
    // srow, srow+128
    const int seg  = tid & 3;
    const int srow = tid >> 2; // 0..127

    const float* gA = tgt + (size_t)b * NT * ND + (size_t)(bt0 + srow) * ND + seg * 8;
    const float* gB = sup + (size_t)b * NS * ND + (size_t)(bs0 + srow) * ND + seg * 8;

    const int wave = tid >> 6;
    const int lane = tid & 63;
    const int wr  = (wave >> 2) * 64;  // 0 or 64
    const int wc  = (wave & 3) * 64;   // 0,64,128,192
    const int lhi = lane >> 4;         // 0..3 (k-group of 8)
    const int llo = lane & 15;

    f32x4 acc[4][4];
#pragma unroll
    for (int m = 0; m < 4; ++m)
#pragma unroll
        for (int n = 0; n < 4; ++n)
            acc[m][n] = (f32x4){0.f, 0.f, 0.f, 0.f};

    float sqa = 0.f, sqb0 = 0.f, sqb1 = 0.f;

    // single prefetch reg set (24 VGPR)
    float4 pA0, pA1, pB0, pB1, pB2, pB3;
    // two fragment sets (cross-barrier prefetch), static names (rule #20)
    short8 xa[4], xb[4], ya[4], yb[4];

    // staging LDS offsets (shorts); (srow+128)>>1 ≡ srow>>1 (mod 4)
    const int pu   = ((seg + (srow >> 1)) & 3) * 8;
    const int offw = srow * BK + pu;

#define LOADT(KK)                                                              \
    do {                                                                       \
        pA0 = *reinterpret_cast<const float4*>(gA + (KK) * BK);                \
        pA1 = *reinterpret_cast<const float4*>(gA + (KK) * BK + 4);            \
        pB0 = *reinterpret_cast<const float4*>(gB + (KK) * BK);                \
        pB1 = *reinterpret_cast<const float4*>(gB + (KK) * BK + 4);            \
        pB2 = *reinterpret_cast<const float4*>(gB + (KK) * BK + 128 * ND);     \
        pB3 = *reinterpret_cast<const float4*>(gB + (KK) * BK + 128 * ND + 4); \
    } while (0)

#define STORET(WB)                                                             \
    do {                                                                       \
        sqa  = ssq4(ssq4(sqa,  pA0), pA1);                                     \
        *reinterpret_cast<short8*>(&As[(WB) * ATSZ + offw]) = cvt8(pA0, pA1);  \
        sqb0 = ssq4(ssq4(sqb0, pB0), pB1);                                     \
        *reinterpret_cast<short8*>(&Bs[(WB) * BTSZ + offw]) = cvt8(pB0, pB1);  \
        sqb1 = ssq4(ssq4(sqb1, pB2), pB3);                                     \
        *reinterpret_cast<short8*>(&Bs[(WB) * BTSZ + offw + 128 * BK]) =       \
            cvt8(pB2, pB3);                                                    \
    } while (0)

#define FRAG_READ(FA, FB, RB)                                                  \
    do {                                                                       \
        _Pragma("unroll") for (int m = 0; m < 4; ++m) {                        \
            const int row = wr + m * 16 + llo;                                 \
            const int off = (RB) * ATSZ + row * BK + (((lhi + (row >> 1)) & 3) * 8); \
            FA[m] = *reinterpret_cast<const short8*>(&As[off]);                \
        }                                                                      \
        _Pragma("unroll") for (int n = 0; n < 4; ++n) {                        \
            const int row = wc + n * 16 + llo;                                 \
            const int off = (RB) * BTSZ + row * BK + (((lhi + (row >> 1)) & 3) * 8); \
            FB[n] = *reinterpret_cast<const short8*>(&Bs[off]);                \
        }                                                                      \
    } while (0)

#define MFMA_BLOCK(FA, FB)                                                     \
    do {                                                                       \
        __builtin_amdgcn_s_setprio(1);                                         \
        _Pragma("unroll") for (int m = 0; m < 4; ++m)                          \
            _Pragma("unroll") for (int n = 0; n < 4; ++n)                      \
                acc[m][n] = __builtin_amdgcn_mfma_f32_16x16x32_bf16(           \
                    FA[m], FB[n], acc[m][n], 0, 0, 0);                         \
        __builtin_amdgcn_s_setprio(0);                                         \
    } while (0)

    // fence: wave's ds ops done, barrier. No vmcnt drain - prefetch loads
    // stay in flight across phases.
#define PHASE_FENCE()                                                          \
    do {                                                                       \
        asm volatile("s_waitcnt lgkmcnt(0)" ::: "memory");                     \
        __builtin_amdgcn_s_barrier();                                          \
        asm volatile("" ::: "memory");                                         \
    } while (0)

#define ROTATE()                                                               \
    do { int t_ = cbuf; cbuf = rbuf; rbuf = wbuf; wbuf = t_; } while (0)

    // prologue: tile0 -> b0; tile1 -> b1; x <- tile0 frags; set <- tile2
    LOADT(0);
    STORET(0);
    LOADT(1);
    PHASE_FENCE();            // b0 visible
    STORET(1);                // tile1 -> b1
    LOADT(2);
    FRAG_READ(xa, xb, 0);     // tile0 frags -> x
    PHASE_FENCE();            // b1 visible; x resolved
    int cbuf = 0, rbuf = 1, wbuf = 2;

    for (int k = 0; k < NK; k += 2) {
        // phase k: MFMA tile k from x (no LDS dep at barrier exit);
        // y <- tile k+1 frags (stable buf, needed after next barrier);
        // STORET tile k+2 (regs from phase k-1); LOADT tile k+3
        if (k + 1 < NK) FRAG_READ(ya, yb, rbuf);
        if (k + 2 < NK) STORET(wbuf);
        if (k + 3 < NK) LOADT(k + 3);
        MFMA_BLOCK(xa, xb);
        PHASE_FENCE();
        ROTATE();
        // phase k+1: MFMA tile k+1 from y; x <- tile k+2; store k+3; load k+4
        if (k + 2 < NK) FRAG_READ(xa, xb, rbuf);
        if (k + 3 < NK) STORET(wbuf);
        if (k + 4 < NK) LOADT(k + 4);
        MFMA_BLOCK(ya, yb);
        PHASE_FENCE();
        ROTATE();
    }

    // norms: row's sumsq lives in its 4 seg-threads; xor 1,2 reduces in-group
    sqa  += __shfl_xor(sqa, 1);
    sqa  += __shfl_xor(sqa, 2);
    sqb0 += __shfl_xor(sqb0, 1);
    sqb0 += __shfl_xor(sqb0, 2);
    sqb1 += __shfl_xor(sqb1, 1);
    sqb1 += __shfl_xor(sqb1, 2);
    if (seg == 0) {
        tn[srow]       = sqrtf(sqa);
        sn[srow]       = sqrtf(sqb0);
        sn[srow + 128] = sqrtf(sqb1);
    }
    __syncthreads();

    float* outp = out + (size_t)b * NT * NS;
#pragma unroll
    for (int m = 0; m < 4; ++m) {
        const int lr0 = wr + m * 16 + lhi * 4;
#pragma unroll
        for (int n = 0; n < 4; ++n) {
            const int lc = wc + n * 16 + llo;
            const float snv = sn[lc];
            const int col = bs0 + lc;
#pragma unroll
            for (int j = 0; j < 4; ++j) {
                const float denom = fmaxf(tn[lr0 + j] * snv, 1e-10f);
                outp[(size_t)(bt0 + lr0 + j) * NS + col] =
                    acc[m][n][j] / denom * 0.5f + 0.5f;
            }
        }
    }
}

extern "C" void kernel_launch(void* const* d_in, const int* in_sizes, int n_in,
                              void* d_out, int out_size, void* d_ws, size_t ws_size,
                              hipStream_t stream) {
    const float* sup = (const float*)d_in[0]; // supports [32,512,1024]
    const float* tgt = (const float*)d_in[1]; // targets  [32,512,1024]
    float* out = (float*)d_out;               // [32,512,512] f32
    (void)in_sizes; (void)n_in; (void)out_size; (void)d_ws; (void)ws_size;
    paircos_mfma<<<dim3(32 * 8), 512, 0, stream>>>(sup, tgt, out);
}